// Round 9
// baseline (378.381 us; speedup 1.0000x reference)
//
#include <hip/hip_runtime.h>

typedef unsigned short u16;
typedef __attribute__((ext_vector_type(8))) short short8x;
typedef __attribute__((ext_vector_type(4))) float f32x4;

#define B_ 2
#define L_ 2048
#define HID_ 2048
#define H_ 8
#define HD_ 256

__device__ __forceinline__ u16 f2bf(float f) {
  union { float f; unsigned u; } v; v.f = f;
  unsigned r = v.u + 0x7FFFu + ((v.u >> 16) & 1u);
  return (u16)(r >> 16);
}
__device__ __forceinline__ float bf2f(u16 u) {
  union { unsigned u; float f; } v; v.u = ((unsigned)u) << 16;
  return v.f;
}

// async global->LDS, 16B per lane. lds ptr must be the wave-uniform base;
// HW adds lane*16.
__device__ __forceinline__ void gload_lds16(const void* g, void* l) {
  __builtin_amdgcn_global_load_lds((const __attribute__((address_space(1))) unsigned*)g,
                                   (__attribute__((address_space(3))) unsigned*)l, 16, 0, 0);
}

// x fp32 -> bf16, same layout. grid = nelem/4/256
__global__ __launch_bounds__(256) void cvt_x_kernel(const float4* __restrict__ in,
                                                    u16* __restrict__ out) {
  int idx = blockIdx.x * 256 + threadIdx.x;
  float4 v = in[idx];
  u16* o = out + (size_t)idx * 4;
  o[0] = f2bf(v.x); o[1] = f2bf(v.y); o[2] = f2bf(v.z); o[3] = f2bf(v.w);
}

// W fp32 [K][N] -> Wt bf16 [N][K] (row stride K). grid (N/32, K/32), block (32,8)
__global__ __launch_bounds__(256) void cvt_wt_kernel(const float* __restrict__ W,
                                                     u16* __restrict__ Wt, int K, int N) {
  __shared__ float tile[32][33];
  int n0 = blockIdx.x * 32, k0 = blockIdx.y * 32;
  int tx = threadIdx.x, ty = threadIdx.y;
#pragma unroll
  for (int i = 0; i < 32; i += 8)
    tile[ty + i][tx] = W[(size_t)(k0 + ty + i) * N + n0 + tx];
  __syncthreads();
#pragma unroll
  for (int i = 0; i < 32; i += 8)
    Wt[(size_t)(n0 + ty + i) * K + k0 + tx] = f2bf(tile[tx][ty + i]);
}

// RoPE + head-permute + optional scale (folds 1/sqrt(HD) into Q).
__global__ __launch_bounds__(256) void rope_kernel(const u16* __restrict__ in,
                                                   u16* __restrict__ out, int nh_shift,
                                                   int in_stride, int in_off, float scale) {
  int idx = blockIdx.x * 256 + threadIdx.x;
  int nh = 1 << nh_shift;
  int d = idx & 127;
  int t = idx >> 7;
  int h = t & (nh - 1);
  int row = t >> nh_shift;  // b*L + l
  int l = row & (L_ - 1);
  int b = row >> 11;
  size_t ibase = (size_t)row * in_stride + in_off + h * 256 + d;
  float x1 = bf2f(in[ibase]);
  float x2 = bf2f(in[ibase + 128]);
  float f = exp2f(-(float)d * (13.287712379549449f / 128.0f));
  float ang = (float)l * f;
  float s, c;
  sincosf(ang, &s, &c);
  size_t obase = ((size_t)(b * nh + h) * L_ + l) * 256 + d;
  out[obase] = f2bf((x1 * c - x2 * s) * scale);
  out[obase + 128] = f2bf((x2 * c + x1 * s) * scale);
}

// qkvproj bf16 [B*L][2560] (V at col off 2304) -> vt bf16 [(b*256+d)][L]
__global__ __launch_bounds__(256) void vt_kernel(const u16* __restrict__ qkvproj,
                                                 u16* __restrict__ vt) {
  int idx = blockIdx.x * 256 + threadIdx.x;  // = (b*256+d)*2048 + l
  int l = idx & 2047;
  int d = (idx >> 11) & 255;
  int b = idx >> 19;
  vt[idx] = qkvproj[((size_t)b * 2048 + l) * 2560 + 2304 + d];
}

// C[M][N] = A[M][K] @ Bt[N][K]^T, bf16 in, fp32 acc, bf16 or fp32 out.
// 128x128 tile, BK=32, 4 waves 2x2; m97 global_load_lds staging;
// T1 bijective chunked XCD swizzle on the flat block index.
template <int F32OUT>
__global__ __launch_bounds__(256) void gemm_bt_kernel(const u16* __restrict__ A,
                                                      const u16* __restrict__ Bt,
                                                      void* __restrict__ Cv,
                                                      int M, int N, int K) {
  __shared__ __attribute__((aligned(16))) u16 As[128 * 32];
  __shared__ __attribute__((aligned(16))) u16 Bs[128 * 32];
  const int tid = threadIdx.x;
  const int lane = tid & 63;
  const int w = tid >> 6;
  const int wr = w >> 1, wc = w & 1;
  // XCD-aware swizzle (bijective; nwg%8==0 in all our launches)
  const int nbx = gridDim.x;
  int flat = blockIdx.y * nbx + blockIdx.x;
  int nwg = nbx * gridDim.y;
  int q8 = nwg >> 3, r8 = nwg & 7;
  int xcd = flat & 7, idx8 = flat >> 3;
  int neu = (xcd < r8 ? xcd * (q8 + 1) : r8 * (q8 + 1) + (xcd - r8) * q8) + idx8;
  const int m0 = (neu / nbx) * 128, n0 = (neu % nbx) * 128;
  const int l15 = lane & 15, l4 = lane >> 4;
  f32x4 acc[4][4] = {};
  for (int kt = 0; kt < K; kt += 32) {
#pragma unroll
    for (int i = 0; i < 2; ++i) {
      int c = tid + i * 256;
      int row = c >> 2, cin = c & 3;  // linear LDS: byte off = c*16
      gload_lds16(A + (size_t)(m0 + row) * K + kt + cin * 8,
                  (char*)As + (i * 256 + w * 64) * 16);
      gload_lds16(Bt + (size_t)(n0 + row) * K + kt + cin * 8,
                  (char*)Bs + (i * 256 + w * 64) * 16);
    }
    __syncthreads();
    short8x a[4], b[4];
#pragma unroll
    for (int m = 0; m < 4; ++m)
      a[m] = *(const short8x*)(&As[(wr * 64 + m * 16 + l15) * 32 + l4 * 8]);
#pragma unroll
    for (int n = 0; n < 4; ++n)
      b[n] = *(const short8x*)(&Bs[(wc * 64 + n * 16 + l15) * 32 + l4 * 8]);
#pragma unroll
    for (int m = 0; m < 4; ++m)
#pragma unroll
      for (int n = 0; n < 4; ++n)
        acc[m][n] = __builtin_amdgcn_mfma_f32_16x16x32_bf16(a[m], b[n], acc[m][n], 0, 0, 0);
    __syncthreads();
  }
#pragma unroll
  for (int m = 0; m < 4; ++m) {
#pragma unroll
    for (int n = 0; n < 4; ++n) {
      int gcol = n0 + wc * 64 + n * 16 + l15;
#pragma unroll
      for (int r = 0; r < 4; ++r) {
        int grow = m0 + wr * 64 + m * 16 + l4 * 4 + r;
        if (F32OUT)
          ((float*)Cv)[(size_t)grow * N + gcol] = acc[m][n][r];
        else
          ((u16*)Cv)[(size_t)grow * N + gcol] = f2bf(acc[m][n][r]);
      }
    }
  }
}

// Flash attention v9 — V direct-from-L2 (no V LDS), K dbuf, 2 blocks/CU.
// qb: [B*H][L][256] (Q pre-scaled), kb: [B][L][256], vt: [B][256][L],
// attn_o: [B*L][H*256].
// grid = 512: j = 31 - (x>>4) (64-row Q-block, heavy first), bh = x&15.
// Wave w owns q-rows j*64 + w*16 .. +15 -> tq == j for ALL waves.
// LDS: K 2x32KB + Ps 8KB = 72KB -> 2 blocks/CU (2 waves/SIMD) with VGPR<=256
// (enforced by launch_bounds(256,2)). V^T fragments are 16B-contiguous in the
// vt layout -> PV reads them straight from L2 (V per batch = 1MB, L2-resident;
// m169 lesson: don't LDS-stage what L2 serves). K prefetch pipeline kept.
__global__ __launch_bounds__(256, 2) void flash_kernel(const u16* __restrict__ qb,
                                                       const u16* __restrict__ kb,
                                                       const u16* __restrict__ vt,
                                                       u16* __restrict__ attn_o) {
  __shared__ __attribute__((aligned(16))) u16 Kbuf[2][64 * 256];  // [k][d], read ^(k&7)<<4
  __shared__ __attribute__((aligned(16))) u16 Ps[4 * 16 * 64];    // per-wave [q16][kv64], ^(q&7)<<4
  const int x = blockIdx.x;
  const int j = 31 - (x >> 4);        // q-block index, heavy first
  const int bh = x & 15;
  const int b = bh >> 3;
  const int h = bh & 7;
  const int tid = threadIdx.x, lane = tid & 63, w = tid >> 6;
  const int l15 = lane & 15, l4 = lane >> 4;
  const int q0 = j * 64 + w * 16;
  const int nt = j + 1;

  const u16* qrow = qb + ((size_t)(b * 8 + h) * L_ + q0 + l15) * 256;
  short8x qf[8];
#pragma unroll
  for (int kc = 0; kc < 8; ++kc)
    qf[kc] = *(const short8x*)(qrow + kc * 32 + l4 * 8);

  f32x4 o[16] = {};
  float mrow = -3e38f, srow = 0.f;    // per-lane: q-row = l15

  const u16* kbase = kb + (size_t)b * (L_ * 256);
  const u16* vbase = vt + (size_t)b * (256 * L_);

  // stage K[64][256] into buffer s: 2048 16B-chunks, 8/thread.
  // linear LDS chunk c holds global col-chunk (c%32)^(row&7) (involution with
  // read XOR).
#define STAGE(t, s)                                                            \
  {                                                                            \
    _Pragma("unroll") for (int i2 = 0; i2 < 8; ++i2) {                         \
      int c = i2 * 256 + tid;                                                  \
      int rk = c >> 5, cck = c & 31, jk = cck ^ (rk & 7);                      \
      gload_lds16(kbase + (size_t)((t) * 64 + rk) * 256 + jk * 8,              \
                  (char*)&Kbuf[s][0] + (i2 * 256 + w * 64) * 16);              \
    }                                                                          \
  }

  STAGE(0, 0);
  asm volatile("s_waitcnt vmcnt(0)" ::: "memory");
  __syncthreads();

  for (int t = 0; t < nt; ++t) {
    if (t + 1 < nt) STAGE(t + 1, (t + 1) & 1);  // prefetch lands under compute
    const char* Kb = (const char*)&Kbuf[t & 1][0];

    // S^T = K Q^T : C row = kv (n*16 + l4*4+r), col = q (l15)
    f32x4 sacc[4] = {};
    __builtin_amdgcn_s_setprio(1);
#pragma unroll
    for (int kc = 0; kc < 8; ++kc)
#pragma unroll
      for (int n = 0; n < 4; ++n) {
        int row = n * 16 + l15;
        short8x kf = *(const short8x*)(Kb +
            ((row * 512 + kc * 64 + l4 * 16) ^ ((row & 7) << 4)));
        sacc[n] = __builtin_amdgcn_mfma_f32_16x16x32_bf16(kf, qf[kc], sacc[n], 0, 0, 0);
      }
    __builtin_amdgcn_s_setprio(0);
    // mask + in-lane softmax for q-row l15 (lane holds 16 kv values)
    float p[4][4];
    const bool dm = (t == j);
    const int qg = q0 + l15;
    float pm = -3e38f;
#pragma unroll
    for (int n = 0; n < 4; ++n)
#pragma unroll
      for (int r = 0; r < 4; ++r) {
        int kvg = t * 64 + n * 16 + l4 * 4 + r;
        float v = sacc[n][r];
        if (dm && (kvg > qg)) v = -1e30f;
        p[n][r] = v;
        pm = fmaxf(pm, v);
      }
    pm = fmaxf(pm, __shfl_xor(pm, 16));
    pm = fmaxf(pm, __shfl_xor(pm, 32));
    // T13: skip rescale when max didn't grow past threshold (P <= e^8, safe)
    const bool defer = __all(pm <= mrow + 8.f);
    float mn, alpha;
    if (defer) {
      mn = mrow;
    } else {
      mn = fmaxf(mrow, pm);
      alpha = __expf(mrow - mn);
      mrow = mn;
    }
    float rs = 0.f;
#pragma unroll
    for (int n = 0; n < 4; ++n)
#pragma unroll
      for (int r = 0; r < 4; ++r) {
        p[n][r] = __expf(p[n][r] - mn);
        rs += p[n][r];
      }
    rs += __shfl_xor(rs, 16);
    rs += __shfl_xor(rs, 32);
    if (defer) {
      srow += rs;
    } else {
      srow = srow * alpha + rs;
      float av[4];
#pragma unroll
      for (int r = 0; r < 4; ++r)
        av[r] = __shfl(alpha, l4 * 4 + r, 16);
#pragma unroll
      for (int ff = 0; ff < 16; ++ff) {
        o[ff][0] *= av[0]; o[ff][1] *= av[1];
        o[ff][2] *= av[2]; o[ff][3] *= av[3];
      }
    }
    // P -> Ps [q=l15][kv], XOR-swizzled, packed pairs via v_cvt_pk_bf16_f32
#pragma unroll
    for (int n = 0; n < 4; ++n)
#pragma unroll
      for (int r = 0; r < 4; r += 2) {
        unsigned pk;
        asm("v_cvt_pk_bf16_f32 %0, %1, %2" : "=v"(pk) : "v"(p[n][r]), "v"(p[n][r + 1]));
        *(unsigned*)((char*)Ps + w * 2048 +
                     ((l15 * 128 + (n * 16 + l4 * 4 + r) * 2) ^ ((l15 & 7) << 4))) = pk;
      }
    asm volatile("s_waitcnt lgkmcnt(0)" ::: "memory");
    short8x paf[2];
#pragma unroll
    for (int kc2 = 0; kc2 < 2; ++kc2)
      paf[kc2] = *(const short8x*)((const char*)Ps + w * 2048 +
          ((l15 * 128 + kc2 * 64 + l4 * 16) ^ ((l15 & 7) << 4)));
    // O += P V : contraction over kv=64; V^T fragments straight from L2
    __builtin_amdgcn_s_setprio(1);
#pragma unroll
    for (int kc2 = 0; kc2 < 2; ++kc2) {
      const u16* vcol = vbase + t * 64 + kc2 * 32 + l4 * 8;
#pragma unroll
      for (int ff = 0; ff < 16; ++ff) {
        short8x vf = *(const short8x*)(vcol + (size_t)(ff * 16 + l15) * L_);
        o[ff] = __builtin_amdgcn_mfma_f32_16x16x32_bf16(paf[kc2], vf, o[ff], 0, 0, 0);
      }
    }
    __builtin_amdgcn_s_setprio(0);
    // K-prefetch (issued at step start) complete + all waves done reading Kbuf
    asm volatile("s_waitcnt vmcnt(0)" ::: "memory");
    __syncthreads();
  }
  // epilogue: srow keyed by q=l15; o rows are q=l4*4+r
  float sv[4];
#pragma unroll
  for (int r = 0; r < 4; ++r)
    sv[r] = __shfl(srow, l4 * 4 + r, 16);
#pragma unroll
  for (int r = 0; r < 4; ++r) {
    float inv = 1.0f / sv[r];
    int grow = q0 + l4 * 4 + r;
    size_t base = ((size_t)b * L_ + grow) * (size_t)(H_ * HD_) + h * 256;
#pragma unroll
    for (int ff = 0; ff < 16; ++ff)
      attn_o[base + ff * 16 + l15] = f2bf(o[ff][r] * inv);
  }
#undef STAGE
}

extern "C" void kernel_launch(void* const* d_in, const int* in_sizes, int n_in,
                              void* d_out, int out_size, void* d_ws, size_t ws_size,
                              hipStream_t stream) {
  const float* x  = (const float*)d_in[0];
  const float* Wq = (const float*)d_in[1];
  const float* Wk = (const float*)d_in[2];
  const float* Wv = (const float*)d_in[3];
  const float* Wo = (const float*)d_in[4];
  // d_in[5] = additive causal mask: semantics reproduced analytically, not read.
  float* out = (float*)d_out;
  char* ws = (char*)d_ws;
  size_t off = 0;
  auto alloc = [&](size_t bytes) {
    void* p = ws + off;
    off = (off + bytes + 255) & ~(size_t)255;
    return p;
  };
  u16* wqkv_t  = (u16*)alloc(2560ull * 2048 * 2);  // rows: 0..2047 Wq^T | 2048..2303 Wk^T | 2304..2559 Wv^T
  u16* wo_t    = (u16*)alloc(2048ull * 2048 * 2);
  u16* xbf     = (u16*)alloc(4096ull * 2048 * 2);  // reused as roped Q
  u16* qkvproj = (u16*)alloc(4096ull * 2560 * 2);  // [B*L][2560]: Q|K|V ; head reused as attn_o
  u16* kb      = (u16*)alloc(4096ull * 256 * 2);
  u16* vtb     = (u16*)alloc(4096ull * 256 * 2);
  u16* qbuf    = xbf;      // alias: x_bf dead after QKV projection
  u16* attn_o  = qkvproj;  // alias: qkvproj dead after rope/vt

  cvt_x_kernel<<<8192, 256, 0, stream>>>((const float4*)x, xbf);
  cvt_wt_kernel<<<dim3(64, 64), dim3(32, 8), 0, stream>>>(Wq, wqkv_t, 2048, 2048);
  cvt_wt_kernel<<<dim3(8, 64),  dim3(32, 8), 0, stream>>>(Wk, wqkv_t + 2048ull * 2048, 2048, 256);
  cvt_wt_kernel<<<dim3(8, 64),  dim3(32, 8), 0, stream>>>(Wv, wqkv_t + 2304ull * 2048, 2048, 256);
  cvt_wt_kernel<<<dim3(64, 64), dim3(32, 8), 0, stream>>>(Wo, wo_t, 2048, 2048);

  // fused QKV projection: M=4096, N=2560, K=2048 (grid 20x32 = 640 blocks)
  gemm_bt_kernel<0><<<dim3(20, 32), 256, 0, stream>>>(xbf, wqkv_t, qkvproj, 4096, 2560, 2048);

  rope_kernel<<<16384, 256, 0, stream>>>(qkvproj, qbuf, 3, 2560, 0, 0.0625f);  // Q (scaled)
  rope_kernel<<<2048, 256, 0, stream>>>(qkvproj, kb, 0, 2560, 2048, 1.0f);     // K
  vt_kernel<<<4096, 256, 0, stream>>>(qkvproj, vtb);

  flash_kernel<<<512, 256, 0, stream>>>(qbuf, kb, vtb, attn_o);

  gemm_bt_kernel<1><<<dim3(16, 32), 256, 0, stream>>>(attn_o, wo_t, out, 4096, 2048, 2048);
}

// Round 10
// 271.169 us; speedup vs baseline: 1.3954x; 1.3954x over previous
//
#include <hip/hip_runtime.h>

typedef unsigned short u16;
typedef __attribute__((ext_vector_type(8))) short short8x;
typedef __attribute__((ext_vector_type(4))) float f32x4;

#define B_ 2
#define L_ 2048
#define HID_ 2048
#define H_ 8
#define HD_ 256

__device__ __forceinline__ u16 f2bf(float f) {
  union { float f; unsigned u; } v; v.f = f;
  unsigned r = v.u + 0x7FFFu + ((v.u >> 16) & 1u);
  return (u16)(r >> 16);
}
__device__ __forceinline__ float bf2f(u16 u) {
  union { unsigned u; float f; } v; v.u = ((unsigned)u) << 16;
  return v.f;
}

// async global->LDS, 16B per lane. lds ptr must be the wave-uniform base;
// HW adds lane*16.
__device__ __forceinline__ void gload_lds16(const void* g, void* l) {
  __builtin_amdgcn_global_load_lds((const __attribute__((address_space(1))) unsigned*)g,
                                   (__attribute__((address_space(3))) unsigned*)l, 16, 0, 0);
}

// x fp32 -> bf16, same layout. grid = nelem/4/256
__global__ __launch_bounds__(256) void cvt_x_kernel(const float4* __restrict__ in,
                                                    u16* __restrict__ out) {
  int idx = blockIdx.x * 256 + threadIdx.x;
  float4 v = in[idx];
  u16* o = out + (size_t)idx * 4;
  o[0] = f2bf(v.x); o[1] = f2bf(v.y); o[2] = f2bf(v.z); o[3] = f2bf(v.w);
}

// W fp32 [K][N] -> Wt bf16 [N][K] (row stride K). grid (N/32, K/32), block (32,8)
__global__ __launch_bounds__(256) void cvt_wt_kernel(const float* __restrict__ W,
                                                     u16* __restrict__ Wt, int K, int N) {
  __shared__ float tile[32][33];
  int n0 = blockIdx.x * 32, k0 = blockIdx.y * 32;
  int tx = threadIdx.x, ty = threadIdx.y;
#pragma unroll
  for (int i = 0; i < 32; i += 8)
    tile[ty + i][tx] = W[(size_t)(k0 + ty + i) * N + n0 + tx];
  __syncthreads();
#pragma unroll
  for (int i = 0; i < 32; i += 8)
    Wt[(size_t)(n0 + ty + i) * K + k0 + tx] = f2bf(tile[tx][ty + i]);
}

// RoPE + head-permute + optional scale (folds 1/sqrt(HD) into Q).
__global__ __launch_bounds__(256) void rope_kernel(const u16* __restrict__ in,
                                                   u16* __restrict__ out, int nh_shift,
                                                   int in_stride, int in_off, float scale) {
  int idx = blockIdx.x * 256 + threadIdx.x;
  int nh = 1 << nh_shift;
  int d = idx & 127;
  int t = idx >> 7;
  int h = t & (nh - 1);
  int row = t >> nh_shift;  // b*L + l
  int l = row & (L_ - 1);
  int b = row >> 11;
  size_t ibase = (size_t)row * in_stride + in_off + h * 256 + d;
  float x1 = bf2f(in[ibase]);
  float x2 = bf2f(in[ibase + 128]);
  float f = exp2f(-(float)d * (13.287712379549449f / 128.0f));
  float ang = (float)l * f;
  float s, c;
  sincosf(ang, &s, &c);
  size_t obase = ((size_t)(b * nh + h) * L_ + l) * 256 + d;
  out[obase] = f2bf((x1 * c - x2 * s) * scale);
  out[obase + 128] = f2bf((x2 * c + x1 * s) * scale);
}

// qkvproj bf16 [B*L][2560] (V at col 2304) -> vt bf16 [(b*256+d)][L].
// 32x32 LDS tile transpose: both global read and write coalesced.
// grid (L/32, 256/32, B), block (32,8)
__global__ __launch_bounds__(256) void vt_kernel(const u16* __restrict__ qkvproj,
                                                 u16* __restrict__ vt) {
  __shared__ u16 tile[32][33];
  int l0 = blockIdx.x * 32, d0 = blockIdx.y * 32, b = blockIdx.z;
  int tx = threadIdx.x, ty = threadIdx.y;
#pragma unroll
  for (int i = 0; i < 32; i += 8)
    tile[ty + i][tx] = qkvproj[((size_t)b * 2048 + l0 + ty + i) * 2560 + 2304 + d0 + tx];
  __syncthreads();
#pragma unroll
  for (int i = 0; i < 32; i += 8)
    vt[((size_t)b * 256 + d0 + ty + i) * 2048 + l0 + tx] = tile[tx][ty + i];
}

// C[M][N] = A[M][K] @ Bt[N][K]^T, bf16 in, fp32 acc, bf16 or fp32 out.
// 128x128 tile, BK=32, 4 waves 2x2; m97 global_load_lds staging;
// T1 bijective chunked XCD swizzle on the flat block index.
template <int F32OUT>
__global__ __launch_bounds__(256) void gemm_bt_kernel(const u16* __restrict__ A,
                                                      const u16* __restrict__ Bt,
                                                      void* __restrict__ Cv,
                                                      int M, int N, int K) {
  __shared__ __attribute__((aligned(16))) u16 As[128 * 32];
  __shared__ __attribute__((aligned(16))) u16 Bs[128 * 32];
  const int tid = threadIdx.x;
  const int lane = tid & 63;
  const int w = tid >> 6;
  const int wr = w >> 1, wc = w & 1;
  // XCD-aware swizzle (bijective; nwg%8==0 in all our launches)
  const int nbx = gridDim.x;
  int flat = blockIdx.y * nbx + blockIdx.x;
  int nwg = nbx * gridDim.y;
  int q8 = nwg >> 3, r8 = nwg & 7;
  int xcd = flat & 7, idx8 = flat >> 3;
  int neu = (xcd < r8 ? xcd * (q8 + 1) : r8 * (q8 + 1) + (xcd - r8) * q8) + idx8;
  const int m0 = (neu / nbx) * 128, n0 = (neu % nbx) * 128;
  const int l15 = lane & 15, l4 = lane >> 4;
  f32x4 acc[4][4] = {};
  for (int kt = 0; kt < K; kt += 32) {
#pragma unroll
    for (int i = 0; i < 2; ++i) {
      int c = tid + i * 256;
      int row = c >> 2, cin = c & 3;  // linear LDS: byte off = c*16
      gload_lds16(A + (size_t)(m0 + row) * K + kt + cin * 8,
                  (char*)As + (i * 256 + w * 64) * 16);
      gload_lds16(Bt + (size_t)(n0 + row) * K + kt + cin * 8,
                  (char*)Bs + (i * 256 + w * 64) * 16);
    }
    __syncthreads();
    short8x a[4], b[4];
#pragma unroll
    for (int m = 0; m < 4; ++m)
      a[m] = *(const short8x*)(&As[(wr * 64 + m * 16 + l15) * 32 + l4 * 8]);
#pragma unroll
    for (int n = 0; n < 4; ++n)
      b[n] = *(const short8x*)(&Bs[(wc * 64 + n * 16 + l15) * 32 + l4 * 8]);
#pragma unroll
    for (int m = 0; m < 4; ++m)
#pragma unroll
      for (int n = 0; n < 4; ++n)
        acc[m][n] = __builtin_amdgcn_mfma_f32_16x16x32_bf16(a[m], b[n], acc[m][n], 0, 0, 0);
    __syncthreads();
  }
#pragma unroll
  for (int m = 0; m < 4; ++m) {
#pragma unroll
    for (int n = 0; n < 4; ++n) {
      int gcol = n0 + wc * 64 + n * 16 + l15;
#pragma unroll
      for (int r = 0; r < 4; ++r) {
        int grow = m0 + wr * 64 + m * 16 + l4 * 4 + r;
        if (F32OUT)
          ((float*)Cv)[(size_t)grow * N + gcol] = acc[m][n][r];
        else
          ((u16*)Cv)[(size_t)grow * N + gcol] = f2bf(acc[m][n][r]);
      }
    }
  }
}

// Flash attention v11 — KVBLK=128: amortize per-step fixed cost (2 barriers,
// vmcnt drain, softmax shfls, P roundtrip) over 2x the MFMA work.
// qb: [B*H][L][256] (Q pre-scaled), kb: [B][L][256], vt: [B][256][L],
// attn_o: [B*L][H*256].
// grid = 512: j = 31 - (x>>4) (64-row Q-block, heavy first), bh = x&15.
// Wave w owns q-rows j*64 + w*16 .. +15. k-tiles of 128: q-block [64j,64j+63]
// lies inside k-tile j>>1, so nt = (j>>1)+1 and ONLY the last tile is masked.
// LDS: K 64KB + V 64KB + Ps 17KB = 145KB -> 1 block/CU (same as v8's 1).
// Single-buffered; stage drain amortized over ~13k cy of compute per step.
__global__ __launch_bounds__(256) void flash_kernel(const u16* __restrict__ qb,
                                                    const u16* __restrict__ kb,
                                                    const u16* __restrict__ vt,
                                                    u16* __restrict__ attn_o) {
  __shared__ __attribute__((aligned(16))) u16 Kbuf[128 * 256];   // [k][d], chunk ^ (k&7)
  __shared__ __attribute__((aligned(16))) u16 Vbuf[256 * 128];   // [d][k], chunk ^ (d&7)
  __shared__ __attribute__((aligned(16))) u16 Ps[4 * 16 * 136];  // per-wave [q16][kv128+pad8]
  const int x = blockIdx.x;
  const int j = 31 - (x >> 4);        // q-block index, heavy first
  const int bh = x & 15;
  const int b = bh >> 3;
  const int h = bh & 7;
  const int tid = threadIdx.x, lane = tid & 63, w = tid >> 6;
  const int l15 = lane & 15, l4 = lane >> 4;
  const int q0 = j * 64 + w * 16;
  const int nt = (j >> 1) + 1;

  const u16* qrow = qb + ((size_t)(b * 8 + h) * L_ + q0 + l15) * 256;
  short8x qf[8];
#pragma unroll
  for (int kc = 0; kc < 8; ++kc)
    qf[kc] = *(const short8x*)(qrow + kc * 32 + l4 * 8);

  f32x4 o[16] = {};
  float mrow = -3e38f, srow = 0.f;    // per-lane: q-row = l15

  const u16* kbase = kb + (size_t)b * (L_ * 256);
  const u16* vbase = vt + (size_t)b * (256 * L_);

  for (int t = 0; t < nt; ++t) {
    // stage K[128][256] + V^T[256][128]: 4096 16B-chunks each, 16/thread each.
    // linear LDS chunk c holds global col-chunk (c%W)^(row&7) (involution with
    // the read-side XOR). K: W=32 chunks/row; V: W=16 chunks/row.
#pragma unroll
    for (int i2 = 0; i2 < 16; ++i2) {
      int c = i2 * 256 + tid;
      int rk = c >> 5, cck = c & 31, jk = cck ^ (rk & 7);
      gload_lds16(kbase + (size_t)(t * 128 + rk) * 256 + jk * 8,
                  (char*)Kbuf + (i2 * 256 + w * 64) * 16);
      int rd = c >> 4, ccv = c & 15, jv = ccv ^ (rd & 7);
      gload_lds16(vbase + (size_t)rd * L_ + t * 128 + jv * 8,
                  (char*)Vbuf + (i2 * 256 + w * 64) * 16);
    }
    asm volatile("s_waitcnt vmcnt(0)" ::: "memory");
    __syncthreads();

    // S^T = K Q^T : C row = kv (n*16 + l4*4+r), col = q (l15); n = 0..7
    f32x4 sacc[8] = {};
    __builtin_amdgcn_s_setprio(1);
#pragma unroll
    for (int kc = 0; kc < 8; ++kc)
#pragma unroll
      for (int n = 0; n < 8; ++n) {
        int row = n * 16 + l15;
        short8x kf = *(const short8x*)((const char*)Kbuf +
            ((row * 512 + kc * 64 + l4 * 16) ^ ((row & 7) << 4)));
        sacc[n] = __builtin_amdgcn_mfma_f32_16x16x32_bf16(kf, qf[kc], sacc[n], 0, 0, 0);
      }
    __builtin_amdgcn_s_setprio(0);
    // mask + in-lane softmax for q-row l15 (lane holds 32 kv values)
    float p[8][4];
    const bool dm = (t == nt - 1);    // only the last k-tile crosses the diagonal
    const int qg = q0 + l15;
    float pm = -3e38f;
#pragma unroll
    for (int n = 0; n < 8; ++n)
#pragma unroll
      for (int r = 0; r < 4; ++r) {
        int kvg = t * 128 + n * 16 + l4 * 4 + r;
        float v = sacc[n][r];
        if (dm && (kvg > qg)) v = -1e30f;
        p[n][r] = v;
        pm = fmaxf(pm, v);
      }
    pm = fmaxf(pm, __shfl_xor(pm, 16));
    pm = fmaxf(pm, __shfl_xor(pm, 32));
    // T13: skip rescale when max didn't grow past threshold (P <= e^8, safe)
    const bool defer = __all(pm <= mrow + 8.f);
    float mn, alpha;
    if (defer) {
      mn = mrow;
    } else {
      mn = fmaxf(mrow, pm);
      alpha = __expf(mrow - mn);
      mrow = mn;
    }
    float rs = 0.f;
#pragma unroll
    for (int n = 0; n < 8; ++n)
#pragma unroll
      for (int r = 0; r < 4; ++r) {
        p[n][r] = __expf(p[n][r] - mn);
        rs += p[n][r];
      }
    rs += __shfl_xor(rs, 16);
    rs += __shfl_xor(rs, 32);
    if (defer) {
      srow += rs;
    } else {
      srow = srow * alpha + rs;
      float av[4];
#pragma unroll
      for (int r = 0; r < 4; ++r)
        av[r] = __shfl(alpha, l4 * 4 + r, 16);
#pragma unroll
      for (int ff = 0; ff < 16; ++ff) {
        o[ff][0] *= av[0]; o[ff][1] *= av[1];
        o[ff][2] *= av[2]; o[ff][3] *= av[3];
      }
    }
    // P -> Ps [q=l15][kv], rows padded to 136 elems (272B, 16B-aligned),
    // packed pairs via v_cvt_pk_bf16_f32
#pragma unroll
    for (int n = 0; n < 8; ++n)
#pragma unroll
      for (int r = 0; r < 4; r += 2) {
        unsigned pk;
        asm("v_cvt_pk_bf16_f32 %0, %1, %2" : "=v"(pk) : "v"(p[n][r]), "v"(p[n][r + 1]));
        *(unsigned*)((char*)Ps + w * 4352 + l15 * 272 + (n * 16 + l4 * 4 + r) * 2) = pk;
      }
    asm volatile("s_waitcnt lgkmcnt(0)" ::: "memory");
    short8x paf[4];
#pragma unroll
    for (int kc2 = 0; kc2 < 4; ++kc2)
      paf[kc2] = *(const short8x*)((const char*)Ps + w * 4352 + l15 * 272 +
                                   kc2 * 64 + l4 * 16);
    // O += P V : contraction over kv=128
    __builtin_amdgcn_s_setprio(1);
#pragma unroll
    for (int kc2 = 0; kc2 < 4; ++kc2)
#pragma unroll
      for (int ff = 0; ff < 16; ++ff) {
        int rd = ff * 16 + l15;
        short8x vf = *(const short8x*)((const char*)Vbuf +
            ((rd * 256 + kc2 * 64 + l4 * 16) ^ ((rd & 7) << 4)));
        o[ff] = __builtin_amdgcn_mfma_f32_16x16x32_bf16(paf[kc2], vf, o[ff], 0, 0, 0);
      }
    __builtin_amdgcn_s_setprio(0);
    __syncthreads();  // all waves done reading before next stage overwrites
  }
  // epilogue: srow keyed by q=l15; o rows are q=l4*4+r
  float sv[4];
#pragma unroll
  for (int r = 0; r < 4; ++r)
    sv[r] = __shfl(srow, l4 * 4 + r, 16);
#pragma unroll
  for (int r = 0; r < 4; ++r) {
    float inv = 1.0f / sv[r];
    int grow = q0 + l4 * 4 + r;
    size_t base = ((size_t)b * L_ + grow) * (size_t)(H_ * HD_) + h * 256;
#pragma unroll
    for (int ff = 0; ff < 16; ++ff)
      attn_o[base + ff * 16 + l15] = f2bf(o[ff][r] * inv);
  }
}

extern "C" void kernel_launch(void* const* d_in, const int* in_sizes, int n_in,
                              void* d_out, int out_size, void* d_ws, size_t ws_size,
                              hipStream_t stream) {
  const float* x  = (const float*)d_in[0];
  const float* Wq = (const float*)d_in[1];
  const float* Wk = (const float*)d_in[2];
  const float* Wv = (const float*)d_in[3];
  const float* Wo = (const float*)d_in[4];
  // d_in[5] = additive causal mask: semantics reproduced analytically, not read.
  float* out = (float*)d_out;
  char* ws = (char*)d_ws;
  size_t off = 0;
  auto alloc = [&](size_t bytes) {
    void* p = ws + off;
    off = (off + bytes + 255) & ~(size_t)255;
    return p;
  };
  u16* wqkv_t  = (u16*)alloc(2560ull * 2048 * 2);  // rows: 0..2047 Wq^T | 2048..2303 Wk^T | 2304..2559 Wv^T
  u16* wo_t    = (u16*)alloc(2048ull * 2048 * 2);
  u16* xbf     = (u16*)alloc(4096ull * 2048 * 2);  // reused as roped Q
  u16* qkvproj = (u16*)alloc(4096ull * 2560 * 2);  // [B*L][2560]: Q|K|V ; head reused as attn_o
  u16* kb      = (u16*)alloc(4096ull * 256 * 2);
  u16* vtb     = (u16*)alloc(4096ull * 256 * 2);
  u16* qbuf    = xbf;      // alias: x_bf dead after QKV projection
  u16* attn_o  = qkvproj;  // alias: qkvproj dead after rope/vt

  cvt_x_kernel<<<8192, 256, 0, stream>>>((const float4*)x, xbf);
  cvt_wt_kernel<<<dim3(64, 64), dim3(32, 8), 0, stream>>>(Wq, wqkv_t, 2048, 2048);
  cvt_wt_kernel<<<dim3(8, 64),  dim3(32, 8), 0, stream>>>(Wk, wqkv_t + 2048ull * 2048, 2048, 256);
  cvt_wt_kernel<<<dim3(8, 64),  dim3(32, 8), 0, stream>>>(Wv, wqkv_t + 2304ull * 2048, 2048, 256);
  cvt_wt_kernel<<<dim3(64, 64), dim3(32, 8), 0, stream>>>(Wo, wo_t, 2048, 2048);

  // fused QKV projection: M=4096, N=2560, K=2048 (grid 20x32 = 640 blocks)
  gemm_bt_kernel<0><<<dim3(20, 32), 256, 0, stream>>>(xbf, wqkv_t, qkvproj, 4096, 2560, 2048);

  rope_kernel<<<16384, 256, 0, stream>>>(qkvproj, qbuf, 3, 2560, 0, 0.0625f);  // Q (scaled)
  rope_kernel<<<2048, 256, 0, stream>>>(qkvproj, kb, 0, 2560, 2048, 1.0f);     // K
  vt_kernel<<<dim3(64, 8, 2), dim3(32, 8), 0, stream>>>(qkvproj, vtb);

  flash_kernel<<<512, 256, 0, stream>>>(qbuf, kb, vtb, attn_o);

  gemm_bt_kernel<1><<<dim3(16, 32), 256, 0, stream>>>(attn_o, wo_t, out, 4096, 2048, 2048);
}

// Round 11
// 237.109 us; speedup vs baseline: 1.5958x; 1.1436x over previous
//
#include <hip/hip_runtime.h>

typedef unsigned short u16;
typedef __attribute__((ext_vector_type(8))) short short8x;
typedef __attribute__((ext_vector_type(4))) float f32x4;

#define B_ 2
#define L_ 2048
#define HID_ 2048
#define H_ 8
#define HD_ 256

__device__ __forceinline__ u16 f2bf(float f) {
  union { float f; unsigned u; } v; v.f = f;
  unsigned r = v.u + 0x7FFFu + ((v.u >> 16) & 1u);
  return (u16)(r >> 16);
}
__device__ __forceinline__ float bf2f(u16 u) {
  union { unsigned u; float f; } v; v.u = ((unsigned)u) << 16;
  return v.f;
}

// async global->LDS, 16B per lane. lds ptr must be the wave-uniform base;
// HW adds lane*16.
__device__ __forceinline__ void gload_lds16(const void* g, void* l) {
  __builtin_amdgcn_global_load_lds((const __attribute__((address_space(1))) unsigned*)g,
                                   (__attribute__((address_space(3))) unsigned*)l, 16, 0, 0);
}

// x fp32 -> bf16, same layout. grid = nelem/4/256
__global__ __launch_bounds__(256) void cvt_x_kernel(const float4* __restrict__ in,
                                                    u16* __restrict__ out) {
  int idx = blockIdx.x * 256 + threadIdx.x;
  float4 v = in[idx];
  u16* o = out + (size_t)idx * 4;
  o[0] = f2bf(v.x); o[1] = f2bf(v.y); o[2] = f2bf(v.z); o[3] = f2bf(v.w);
}

// W fp32 [K][N] -> Wt bf16 [N][K] (row stride K). grid (N/32, K/32), block (32,8)
__global__ __launch_bounds__(256) void cvt_wt_kernel(const float* __restrict__ W,
                                                     u16* __restrict__ Wt, int K, int N) {
  __shared__ float tile[32][33];
  int n0 = blockIdx.x * 32, k0 = blockIdx.y * 32;
  int tx = threadIdx.x, ty = threadIdx.y;
#pragma unroll
  for (int i = 0; i < 32; i += 8)
    tile[ty + i][tx] = W[(size_t)(k0 + ty + i) * N + n0 + tx];
  __syncthreads();
#pragma unroll
  for (int i = 0; i < 32; i += 8)
    Wt[(size_t)(n0 + ty + i) * K + k0 + tx] = f2bf(tile[tx][ty + i]);
}

// RoPE + head-permute + optional scale (folds 1/sqrt(HD) into Q).
__global__ __launch_bounds__(256) void rope_kernel(const u16* __restrict__ in,
                                                   u16* __restrict__ out, int nh_shift,
                                                   int in_stride, int in_off, float scale) {
  int idx = blockIdx.x * 256 + threadIdx.x;
  int nh = 1 << nh_shift;
  int d = idx & 127;
  int t = idx >> 7;
  int h = t & (nh - 1);
  int row = t >> nh_shift;  // b*L + l
  int l = row & (L_ - 1);
  int b = row >> 11;
  size_t ibase = (size_t)row * in_stride + in_off + h * 256 + d;
  float x1 = bf2f(in[ibase]);
  float x2 = bf2f(in[ibase + 128]);
  float f = exp2f(-(float)d * (13.287712379549449f / 128.0f));
  float ang = (float)l * f;
  float s, c;
  sincosf(ang, &s, &c);
  size_t obase = ((size_t)(b * nh + h) * L_ + l) * 256 + d;
  out[obase] = f2bf((x1 * c - x2 * s) * scale);
  out[obase + 128] = f2bf((x2 * c + x1 * s) * scale);
}

// qkvproj bf16 [B*L][2560] (V at col 2304) -> vt bf16 [(b*256+d)][L].
// 32x32 LDS tile transpose: both global read and write coalesced.
// grid (L/32, 256/32, B), block (32,8)
__global__ __launch_bounds__(256) void vt_kernel(const u16* __restrict__ qkvproj,
                                                 u16* __restrict__ vt) {
  __shared__ u16 tile[32][33];
  int l0 = blockIdx.x * 32, d0 = blockIdx.y * 32, b = blockIdx.z;
  int tx = threadIdx.x, ty = threadIdx.y;
#pragma unroll
  for (int i = 0; i < 32; i += 8)
    tile[ty + i][tx] = qkvproj[((size_t)b * 2048 + l0 + ty + i) * 2560 + 2304 + d0 + tx];
  __syncthreads();
#pragma unroll
  for (int i = 0; i < 32; i += 8)
    vt[((size_t)b * 256 + d0 + ty + i) * 2048 + l0 + tx] = tile[tx][ty + i];
}

// C[M][N] = A[M][K] @ Bt[N][K]^T, bf16 in, fp32 acc, bf16 or fp32 out.
// 128x128 tile, BK=32, 4 waves 2x2; m97 global_load_lds staging;
// T1 bijective chunked XCD swizzle on the flat block index.
template <int F32OUT>
__global__ __launch_bounds__(256) void gemm_bt_kernel(const u16* __restrict__ A,
                                                      const u16* __restrict__ Bt,
                                                      void* __restrict__ Cv,
                                                      int M, int N, int K) {
  __shared__ __attribute__((aligned(16))) u16 As[128 * 32];
  __shared__ __attribute__((aligned(16))) u16 Bs[128 * 32];
  const int tid = threadIdx.x;
  const int lane = tid & 63;
  const int w = tid >> 6;
  const int wr = w >> 1, wc = w & 1;
  // XCD-aware swizzle (bijective; nwg%8==0 in all our launches)
  const int nbx = gridDim.x;
  int flat = blockIdx.y * nbx + blockIdx.x;
  int nwg = nbx * gridDim.y;
  int q8 = nwg >> 3, r8 = nwg & 7;
  int xcd = flat & 7, idx8 = flat >> 3;
  int neu = (xcd < r8 ? xcd * (q8 + 1) : r8 * (q8 + 1) + (xcd - r8) * q8) + idx8;
  const int m0 = (neu / nbx) * 128, n0 = (neu % nbx) * 128;
  const int l15 = lane & 15, l4 = lane >> 4;
  f32x4 acc[4][4] = {};
  for (int kt = 0; kt < K; kt += 32) {
#pragma unroll
    for (int i = 0; i < 2; ++i) {
      int c = tid + i * 256;
      int row = c >> 2, cin = c & 3;  // linear LDS: byte off = c*16
      gload_lds16(A + (size_t)(m0 + row) * K + kt + cin * 8,
                  (char*)As + (i * 256 + w * 64) * 16);
      gload_lds16(Bt + (size_t)(n0 + row) * K + kt + cin * 8,
                  (char*)Bs + (i * 256 + w * 64) * 16);
    }
    __syncthreads();
    short8x a[4], b[4];
#pragma unroll
    for (int m = 0; m < 4; ++m)
      a[m] = *(const short8x*)(&As[(wr * 64 + m * 16 + l15) * 32 + l4 * 8]);
#pragma unroll
    for (int n = 0; n < 4; ++n)
      b[n] = *(const short8x*)(&Bs[(wc * 64 + n * 16 + l15) * 32 + l4 * 8]);
#pragma unroll
    for (int m = 0; m < 4; ++m)
#pragma unroll
      for (int n = 0; n < 4; ++n)
        acc[m][n] = __builtin_amdgcn_mfma_f32_16x16x32_bf16(a[m], b[n], acc[m][n], 0, 0, 0);
    __syncthreads();
  }
#pragma unroll
  for (int m = 0; m < 4; ++m) {
#pragma unroll
    for (int n = 0; n < 4; ++n) {
      int gcol = n0 + wc * 64 + n * 16 + l15;
#pragma unroll
      for (int r = 0; r < 4; ++r) {
        int grow = m0 + wr * 64 + m * 16 + l4 * 4 + r;
        if (F32OUT)
          ((float*)Cv)[(size_t)grow * N + gcol] = acc[m][n][r];
        else
          ((u16*)Cv)[(size_t)grow * N + gcol] = f2bf(acc[m][n][r]);
      }
    }
  }
}

// Flash attention v12 — 8-wave blocks, heavy/light q-block pairing in-block,
// K+V dbuf with prefetch (v8 datapath).
// qb: [B*H][L][256] (Q pre-scaled), kb: [B][L][256], vt: [B][256][L],
// attn_o: [B*L][H*256].
// grid = 256 (= #CUs, all co-resident): p = x>>4 (0..15), bh = x&15.
// Waves 0-3 own q-block jA = 31-p (rows jA*64 + (w&3)*16); waves 4-7 own
// jB = p. Shared k-tile stream 0..jA (jB <= jA); light waves skip compute
// (but not barriers/staging) for t > jB. Each SIMD hosts one heavy + one
// light wave -> 2 waves/SIMD while both live; busy-steps/SIMD = 33 for every
// block; wall = 32-p steps.
// LDS: K 2x32KB + V 2x32KB + Ps 16KB = 147.5KB -> 1 block/CU.
__global__ __launch_bounds__(512) void flash_kernel(const u16* __restrict__ qb,
                                                    const u16* __restrict__ kb,
                                                    const u16* __restrict__ vt,
                                                    u16* __restrict__ attn_o) {
  __shared__ __attribute__((aligned(16))) u16 Kbuf[2][64 * 256];  // [k][d], read ^(k&7)<<4
  __shared__ __attribute__((aligned(16))) u16 Vbuf[2][256 * 64];  // [d][k], read ^(d&7)<<4
  __shared__ __attribute__((aligned(16))) u16 Ps[8 * 16 * 64];    // per-wave [q16][kv64], ^(q&7)<<4
  const int x = blockIdx.x;
  const int p = x >> 4;               // pair index 0..15
  const int bh = x & 15;
  const int b = bh >> 3;
  const int h = bh & 7;
  const int tid = threadIdx.x, lane = tid & 63, w = tid >> 6;
  const int l15 = lane & 15, l4 = lane >> 4;
  const int j = (w < 4) ? (31 - p) : p;   // this wave's 64-row q-block
  const int q0 = j * 64 + (w & 3) * 16;
  const int nt = (31 - p) + 1;            // shared k-step count (heavy bound)

  const u16* qrow = qb + ((size_t)(b * 8 + h) * L_ + q0 + l15) * 256;
  short8x qf[8];
#pragma unroll
  for (int kc = 0; kc < 8; ++kc)
    qf[kc] = *(const short8x*)(qrow + kc * 32 + l4 * 8);

  f32x4 o[16] = {};
  float mrow = -3e38f, srow = 0.f;    // per-lane: q-row = l15

  const u16* kbase = kb + (size_t)b * (L_ * 256);
  const u16* vbase = vt + (size_t)b * (256 * L_);

  // stage K[64][256] + V^T[256][64] into buffer s: 2048 16B-chunks each,
  // 4/thread each (512 threads). linear LDS chunk c holds global col-chunk
  // (c%W)^(row&7) (involution with read XOR). K: W=32; V: W=8.
#define STAGE(t, s)                                                            \
  {                                                                            \
    _Pragma("unroll") for (int i2 = 0; i2 < 4; ++i2) {                         \
      int c = i2 * 512 + tid;                                                  \
      int rk = c >> 5, cck = c & 31, jk = cck ^ (rk & 7);                      \
      gload_lds16(kbase + (size_t)((t) * 64 + rk) * 256 + jk * 8,              \
                  (char*)&Kbuf[s][0] + (i2 * 512 + w * 64) * 16);              \
      int rd = c >> 3, ccv = c & 7, jv = ccv ^ (rd & 7);                       \
      gload_lds16(vbase + (size_t)rd * L_ + (t) * 64 + jv * 8,                 \
                  (char*)&Vbuf[s][0] + (i2 * 512 + w * 64) * 16);              \
    }                                                                          \
  }

  STAGE(0, 0);
  asm volatile("s_waitcnt vmcnt(0)" ::: "memory");
  __syncthreads();

  for (int t = 0; t < nt; ++t) {
    if (t + 1 < nt) STAGE(t + 1, (t + 1) & 1);  // prefetch lands under compute
    if (t <= j) {
      const char* Kb = (const char*)&Kbuf[t & 1][0];
      const char* Vb = (const char*)&Vbuf[t & 1][0];

      // S^T = K Q^T : C row = kv (n*16 + l4*4+r), col = q (l15)
      f32x4 sacc[4] = {};
      __builtin_amdgcn_s_setprio(1);
#pragma unroll
      for (int kc = 0; kc < 8; ++kc)
#pragma unroll
        for (int n = 0; n < 4; ++n) {
          int row = n * 16 + l15;
          short8x kf = *(const short8x*)(Kb +
              ((row * 512 + kc * 64 + l4 * 16) ^ ((row & 7) << 4)));
          sacc[n] = __builtin_amdgcn_mfma_f32_16x16x32_bf16(kf, qf[kc], sacc[n], 0, 0, 0);
        }
      __builtin_amdgcn_s_setprio(0);
      // mask + in-lane softmax for q-row l15 (lane holds 16 kv values)
      float pp[4][4];
      const bool dm = (t == j);
      const int qg = q0 + l15;
      float pm = -3e38f;
#pragma unroll
      for (int n = 0; n < 4; ++n)
#pragma unroll
        for (int r = 0; r < 4; ++r) {
          int kvg = t * 64 + n * 16 + l4 * 4 + r;
          float v = sacc[n][r];
          if (dm && (kvg > qg)) v = -1e30f;
          pp[n][r] = v;
          pm = fmaxf(pm, v);
        }
      pm = fmaxf(pm, __shfl_xor(pm, 16));
      pm = fmaxf(pm, __shfl_xor(pm, 32));
      // T13: skip rescale when max didn't grow past threshold (P <= e^8, safe)
      const bool defer = __all(pm <= mrow + 8.f);
      float mn, alpha;
      if (defer) {
        mn = mrow;
      } else {
        mn = fmaxf(mrow, pm);
        alpha = __expf(mrow - mn);
        mrow = mn;
      }
      float rs = 0.f;
#pragma unroll
      for (int n = 0; n < 4; ++n)
#pragma unroll
        for (int r = 0; r < 4; ++r) {
          pp[n][r] = __expf(pp[n][r] - mn);
          rs += pp[n][r];
        }
      rs += __shfl_xor(rs, 16);
      rs += __shfl_xor(rs, 32);
      if (defer) {
        srow += rs;
      } else {
        srow = srow * alpha + rs;
        float av[4];
#pragma unroll
        for (int r = 0; r < 4; ++r)
          av[r] = __shfl(alpha, l4 * 4 + r, 16);
#pragma unroll
        for (int ff = 0; ff < 16; ++ff) {
          o[ff][0] *= av[0]; o[ff][1] *= av[1];
          o[ff][2] *= av[2]; o[ff][3] *= av[3];
        }
      }
      // P -> Ps [q=l15][kv], XOR-swizzled, packed pairs via v_cvt_pk_bf16_f32
#pragma unroll
      for (int n = 0; n < 4; ++n)
#pragma unroll
        for (int r = 0; r < 4; r += 2) {
          unsigned pk;
          asm("v_cvt_pk_bf16_f32 %0, %1, %2" : "=v"(pk) : "v"(pp[n][r]), "v"(pp[n][r + 1]));
          *(unsigned*)((char*)Ps + w * 2048 +
                       ((l15 * 128 + (n * 16 + l4 * 4 + r) * 2) ^ ((l15 & 7) << 4))) = pk;
        }
      asm volatile("s_waitcnt lgkmcnt(0)" ::: "memory");
      short8x paf[2];
#pragma unroll
      for (int kc2 = 0; kc2 < 2; ++kc2)
        paf[kc2] = *(const short8x*)((const char*)Ps + w * 2048 +
            ((l15 * 128 + kc2 * 64 + l4 * 16) ^ ((l15 & 7) << 4)));
      // O += P V : contraction over kv=64
      __builtin_amdgcn_s_setprio(1);
#pragma unroll
      for (int kc2 = 0; kc2 < 2; ++kc2)
#pragma unroll
        for (int ff = 0; ff < 16; ++ff) {
          int rd = ff * 16 + l15;
          short8x vf = *(const short8x*)(Vb +
              ((rd * 128 + kc2 * 64 + l4 * 16) ^ ((rd & 7) << 4)));
          o[ff] = __builtin_amdgcn_mfma_f32_16x16x32_bf16(paf[kc2], vf, o[ff], 0, 0, 0);
        }
      __builtin_amdgcn_s_setprio(0);
    }
    // prefetch (issued at step start) complete + all waves done reading bufs
    asm volatile("s_waitcnt vmcnt(0)" ::: "memory");
    __syncthreads();
  }
  // epilogue: srow keyed by q=l15; o rows are q=l4*4+r
  float sv[4];
#pragma unroll
  for (int r = 0; r < 4; ++r)
    sv[r] = __shfl(srow, l4 * 4 + r, 16);
#pragma unroll
  for (int r = 0; r < 4; ++r) {
    float inv = 1.0f / sv[r];
    int grow = q0 + l4 * 4 + r;
    size_t base = ((size_t)b * L_ + grow) * (size_t)(H_ * HD_) + h * 256;
#pragma unroll
    for (int ff = 0; ff < 16; ++ff)
      attn_o[base + ff * 16 + l15] = f2bf(o[ff][r] * inv);
  }
#undef STAGE
}

extern "C" void kernel_launch(void* const* d_in, const int* in_sizes, int n_in,
                              void* d_out, int out_size, void* d_ws, size_t ws_size,
                              hipStream_t stream) {
  const float* x  = (const float*)d_in[0];
  const float* Wq = (const float*)d_in[1];
  const float* Wk = (const float*)d_in[2];
  const float* Wv = (const float*)d_in[3];
  const float* Wo = (const float*)d_in[4];
  // d_in[5] = additive causal mask: semantics reproduced analytically, not read.
  float* out = (float*)d_out;
  char* ws = (char*)d_ws;
  size_t off = 0;
  auto alloc = [&](size_t bytes) {
    void* p = ws + off;
    off = (off + bytes + 255) & ~(size_t)255;
    return p;
  };
  u16* wqkv_t  = (u16*)alloc(2560ull * 2048 * 2);  // rows: 0..2047 Wq^T | 2048..2303 Wk^T | 2304..2559 Wv^T
  u16* wo_t    = (u16*)alloc(2048ull * 2048 * 2);
  u16* xbf     = (u16*)alloc(4096ull * 2048 * 2);  // reused as roped Q
  u16* qkvproj = (u16*)alloc(4096ull * 2560 * 2);  // [B*L][2560]: Q|K|V ; head reused as attn_o
  u16* kb      = (u16*)alloc(4096ull * 256 * 2);
  u16* vtb     = (u16*)alloc(4096ull * 256 * 2);
  u16* qbuf    = xbf;      // alias: x_bf dead after QKV projection
  u16* attn_o  = qkvproj;  // alias: qkvproj dead after rope/vt

  cvt_x_kernel<<<8192, 256, 0, stream>>>((const float4*)x, xbf);
  cvt_wt_kernel<<<dim3(64, 64), dim3(32, 8), 0, stream>>>(Wq, wqkv_t, 2048, 2048);
  cvt_wt_kernel<<<dim3(8, 64),  dim3(32, 8), 0, stream>>>(Wk, wqkv_t + 2048ull * 2048, 2048, 256);
  cvt_wt_kernel<<<dim3(8, 64),  dim3(32, 8), 0, stream>>>(Wv, wqkv_t + 2304ull * 2048, 2048, 256);
  cvt_wt_kernel<<<dim3(64, 64), dim3(32, 8), 0, stream>>>(Wo, wo_t, 2048, 2048);

  // fused QKV projection: M=4096, N=2560, K=2048 (grid 20x32 = 640 blocks)
  gemm_bt_kernel<0><<<dim3(20, 32), 256, 0, stream>>>(xbf, wqkv_t, qkvproj, 4096, 2560, 2048);

  rope_kernel<<<16384, 256, 0, stream>>>(qkvproj, qbuf, 3, 2560, 0, 0.0625f);  // Q (scaled)
  rope_kernel<<<2048, 256, 0, stream>>>(qkvproj, kb, 0, 2560, 2048, 1.0f);     // K
  vt_kernel<<<dim3(64, 8, 2), dim3(32, 8), 0, stream>>>(qkvproj, vtb);

  flash_kernel<<<256, 512, 0, stream>>>(qbuf, kb, vtb, attn_o);

  gemm_bt_kernel<1><<<dim3(16, 32), 256, 0, stream>>>(attn_o, wo_t, out, 4096, 2048, 2048);
}